// Round 3
// baseline (508.401 us; speedup 1.0000x reference)
//
#include <hip/hip_runtime.h>

#define DIMC 384
#define NHEADS 12
#define NTOK 144
#define TABLEN 529
#define BWIN 512
#define NWIN 16
#define CPBH 512

typedef unsigned short u16;
typedef unsigned int u32;
typedef __attribute__((ext_vector_type(8))) short short8;
typedef __attribute__((ext_vector_type(4))) float f32x4;

#define MFMA(a, b, c) __builtin_amdgcn_mfma_f32_16x16x32_bf16((a), (b), (c), 0, 0, 0)

__device__ __forceinline__ u16 f2bf(float f) {
  union { float f; u32 u; } v; v.f = f;
  u32 r = v.u + 0x7fffu + ((v.u >> 16) & 1u);
  return (u16)(r >> 16);
}
__device__ __forceinline__ u32 pk2(float a, float b) {
  return (u32)f2bf(a) | ((u32)f2bf(b) << 16);
}
__device__ __forceinline__ u32 cvtpk(float lo, float hi) {
  u32 r;
  asm("v_cvt_pk_bf16_f32 %0, %1, %2" : "=v"(r) : "v"(lo), "v"(hi));
  return r;
}

// ---------------- f32 -> bf16 bulk convert (8 elems/thread) ----------------
__global__ __launch_bounds__(256) void cvt_bf16(const float* __restrict__ in,
                                                u16* __restrict__ out, int n8) {
  int i = blockIdx.x * 256 + threadIdx.x;
  if (i >= n8) return;
  const float4* p = (const float4*)(in + (size_t)i * 8);
  float4 a = p[0], b = p[1];
  uint4 r;
  r.x = pk2(a.x, a.y); r.y = pk2(a.z, a.w);
  r.z = pk2(b.x, b.y); r.w = pk2(b.z, b.w);
  *(uint4*)(out + (size_t)i * 8) = r;
}

// ---------------- CPB-MLP: tabT[h][529] = 16*sigmoid(mlp) + per-head scales ----------------
__global__ void cpb_kernel(const float* __restrict__ rct,
                           const float* __restrict__ w1,
                           const float* __restrict__ b1,
                           const float* __restrict__ w2,
                           const float* __restrict__ logit_scale,
                           float* __restrict__ tabT,
                           float* __restrict__ scalev) {
  int t = blockIdx.x * blockDim.x + threadIdx.x;
  if (t < NHEADS) scalev[t] = __expf(fminf(logit_scale[t], 4.60517018598809f));
  if (t >= TABLEN * NHEADS) return;
  int i = t / NHEADS, h = t % NHEADS;
  float c0 = rct[2 * i], c1 = rct[2 * i + 1];
  const float* w2h = w2 + (size_t)h * CPBH;
  float acc = 0.f;
  for (int k = 0; k < CPBH; ++k) {
    float hv = fmaxf(0.f, fmaf(c0, w1[2 * k], fmaf(c1, w1[2 * k + 1], b1[k])));
    acc = fmaf(hv, w2h[k], acc);
  }
  tabT[h * TABLEN + i] = 16.f / (1.f + __expf(-acc));
}

// ---------------- fused QKV-projection + cosine attention per (window b, head h) ----------------
// 192 threads = 3 waves; wave wv owns query rows [48wv, 48wv+48).
// LDS (u16 units), XOR-swizzled rows (block' = blk ^ (row&7), rows 128B):
//   qn  [144][64] @0      (aliased by per-ck P chunks in PV phase)
//   xs  [144][64] @9216   (phase1)  | kn [144][64] @9216  (phase2+)
//   wsm [96][64]  @18432  (phase1)  | vT [32][192] @18432 (phase2+)
//   tab 529 f32   @24576
__global__ __launch_bounds__(192, 3) void attn_fused(
    const u16* __restrict__ xb, const u16* __restrict__ wb,
    const float* __restrict__ q_bias, const float* __restrict__ k_bias,
    const float* __restrict__ v_bias, const int* __restrict__ rpi,
    const float* __restrict__ mask, const float* __restrict__ tabT,
    const float* __restrict__ scalev, u16* __restrict__ ctx) {
  __shared__ u16 smem[25640];
  u16* qn = smem;
  u16* xs = smem + 9216;
  u16* wsm = smem + 18432;
  u16* kn = smem + 9216;
  u16* vT = smem + 18432;
  float* tab = (float*)(smem + 24576);

  int bid = blockIdx.x;
  int b = bid / NHEADS, h = bid - b * NHEADS;
  int tid = threadIdx.x;
  int lane = tid & 63, wv = tid >> 6;
  int g = lane >> 4, c = lane & 15;
  int rbase = wv * 48;

  for (int i = tid; i < TABLEN; i += 192) tab[i] = tabT[h * TABLEN + i];

  // ---- phase 1: QKV projection (per-head 96 outputs), K chunked by 32 ----
  f32x4 acc[3][6];
#pragma unroll
  for (int i = 0; i < 3; ++i)
#pragma unroll
    for (int j = 0; j < 6; ++j) acc[i][j] = (f32x4){0.f, 0.f, 0.f, 0.f};

  int r4 = tid >> 2, s8 = (tid & 3) * 8;
  int xswz = ((tid & 3) ^ (r4 & 7)) * 8;  // swizzled block offset for staging writes
  uint4 px[3], pw[2];
#pragma unroll
  for (int p = 0; p < 3; ++p)
    px[p] = *(const uint4*)(xb + ((size_t)b * NTOK + p * 48 + r4) * DIMC + s8);
#pragma unroll
  for (int p = 0; p < 2; ++p) {
    int row = p * 48 + r4;
    int wrow = (row >> 5) * DIMC + h * 32 + (row & 31);
    pw[p] = *(const uint4*)(wb + (size_t)wrow * DIMC + s8);
  }

  for (int t = 0; t < 12; ++t) {
#pragma unroll
    for (int p = 0; p < 3; ++p)
      *(uint4*)(xs + (p * 48 + r4) * 64 + xswz) = px[p];
#pragma unroll
    for (int p = 0; p < 2; ++p)
      *(uint4*)(wsm + (p * 48 + r4) * 64 + xswz) = pw[p];
    __syncthreads();
    if (t < 11) {
      int k0 = (t + 1) * 32;
#pragma unroll
      for (int p = 0; p < 3; ++p)
        px[p] = *(const uint4*)(xb + ((size_t)b * NTOK + p * 48 + r4) * DIMC + k0 + s8);
#pragma unroll
      for (int p = 0; p < 2; ++p) {
        int row = p * 48 + r4;
        int wrow = (row >> 5) * DIMC + h * 32 + (row & 31);
        pw[p] = *(const uint4*)(wb + (size_t)wrow * DIMC + k0 + s8);
      }
    }
    int fswz = (g ^ (c & 7)) * 8;
    short8 ax[3];
#pragma unroll
    for (int nt = 0; nt < 3; ++nt)
      ax[nt] = *(const short8*)(xs + (rbase + nt * 16 + c) * 64 + fswz);
#pragma unroll
    for (int ni = 0; ni < 6; ++ni) {
      short8 bw = *(const short8*)(wsm + (ni * 16 + c) * 64 + fswz);
#pragma unroll
      for (int nt = 0; nt < 3; ++nt) acc[nt][ni] = MFMA(ax[nt], bw, acc[nt][ni]);
    }
    __syncthreads();
  }

  // ---- phase 2: bias + cosine-normalize, write qn/kn (u16) + vT (packed u32) ----
  float sch = scalev[h];
  float qb0 = q_bias[h * 32 + c], qb1 = q_bias[h * 32 + 16 + c];
  float kb0 = k_bias[h * 32 + c], kb1 = k_bias[h * 32 + 16 + c];
  float vb0 = v_bias[h * 32 + c], vb1 = v_bias[h * 32 + 16 + c];
#pragma unroll
  for (int nt = 0; nt < 3; ++nt) {
    float v0a[4], v1a[4];
#pragma unroll
    for (int r = 0; r < 4; ++r) {
      int row = rbase + nt * 16 + g * 4 + r;
      int rw7 = row & 7;
      float q0 = acc[nt][0][r] + qb0, q1 = acc[nt][1][r] + qb1;
      float ssq = q0 * q0 + q1 * q1;
      ssq += __shfl_xor(ssq, 1); ssq += __shfl_xor(ssq, 2);
      ssq += __shfl_xor(ssq, 4); ssq += __shfl_xor(ssq, 8);
      float siq = sch / sqrtf(ssq);
      qn[row * 64 + ((c >> 3) ^ rw7) * 8 + (c & 7)] = f2bf(q0 * siq);
      qn[row * 64 + (((c + 16) >> 3) ^ rw7) * 8 + (c & 7)] = f2bf(q1 * siq);
      float k0v = acc[nt][2][r] + kb0, k1v = acc[nt][3][r] + kb1;
      float ssk = k0v * k0v + k1v * k1v;
      ssk += __shfl_xor(ssk, 1); ssk += __shfl_xor(ssk, 2);
      ssk += __shfl_xor(ssk, 4); ssk += __shfl_xor(ssk, 8);
      float sik = 1.f / sqrtf(ssk);
      kn[row * 64 + ((c >> 3) ^ rw7) * 8 + (c & 7)] = f2bf(k0v * sik);
      kn[row * 64 + (((c + 16) >> 3) ^ rw7) * 8 + (c & 7)] = f2bf(k1v * sik);
      v0a[r] = acc[nt][4][r] + vb0;
      v1a[r] = acc[nt][5][r] + vb1;
    }
    int m0 = rbase + nt * 16 + g * 4;
    int blk = m0 >> 3;
    int sub = m0 & 7;  // = 4*(g&1)
    u16* p0 = vT + c * 192 + (blk ^ (c & 7)) * 8 + sub;
    u16* p1 = vT + (c + 16) * 192 + (blk ^ (c & 7)) * 8 + sub;
    *(u32*)p0 = cvtpk(v0a[0], v0a[1]);
    *(u32*)(p0 + 2) = cvtpk(v0a[2], v0a[3]);
    *(u32*)p1 = cvtpk(v1a[0], v1a[1]);
    *(u32*)(p1 + 2) = cvtpk(v1a[2], v1a[3]);
  }
  if (tid < 64) {  // zero vT m-pad (144..159)
    int d = tid >> 1, t = tid & 1;
    uint4 z4 = {0u, 0u, 0u, 0u};
    *(uint4*)(vT + d * 192 + ((18 + t) ^ (d & 7)) * 8) = z4;
  }
  __syncthreads();

  // ---- phases 3-5 per nt: S^T = kn.qn^T, softmax in-lane, packed-P bounce, PV ----
  short8 ak[9];
  int fswz = (g ^ (c & 7)) * 8;
#pragma unroll
  for (int mt = 0; mt < 9; ++mt)
    ak[mt] = *(const short8*)(kn + (mt * 16 + c) * 64 + fswz);
  int w = b & (NWIN - 1);

#pragma unroll
  for (int nt = 0; nt < 3; ++nt) {
    int n = rbase + nt * 16 + c;
    short8 bq = *(const short8*)(qn + n * 64 + fswz);
    f32x4 ST[9];
#pragma unroll
    for (int mt = 0; mt < 9; ++mt) {
      f32x4 z = (f32x4){0.f, 0.f, 0.f, 0.f};
      ST[mt] = MFMA(ak[mt], bq, z);
    }
    // bias add + max
    const int* rrow = rpi + n * NTOK;
    const float* mrow = mask + ((size_t)(w * NTOK + n)) * NTOK;
    float mx = -1e30f;
#pragma unroll
    for (int mt = 0; mt < 9; ++mt) {
      int4 idx = *(const int4*)(rrow + mt * 16 + g * 4);
      float4 mk = *(const float4*)(mrow + mt * 16 + g * 4);
      ST[mt][0] += tab[idx.x] + mk.x;
      ST[mt][1] += tab[idx.y] + mk.y;
      ST[mt][2] += tab[idx.z] + mk.z;
      ST[mt][3] += tab[idx.w] + mk.w;
      mx = fmaxf(mx, fmaxf(fmaxf(ST[mt][0], ST[mt][1]), fmaxf(ST[mt][2], ST[mt][3])));
    }
    mx = fmaxf(mx, __shfl_xor(mx, 16));
    mx = fmaxf(mx, __shfl_xor(mx, 32));
    float sum = 0.f;
#pragma unroll
    for (int mt = 0; mt < 9; ++mt) {
#pragma unroll
      for (int r = 0; r < 4; ++r) {
        float p = __expf(ST[mt][r] - mx);
        ST[mt][r] = p;
        sum += p;
      }
    }
    sum += __shfl_xor(sum, 16);
    sum += __shfl_xor(sum, 32);
    float rinv = 1.f / sum;

    // PV: per-32-m-chunk packed-P bounce into (dead) qn region, rows wave-private
    f32x4 po0 = (f32x4){0.f, 0.f, 0.f, 0.f};
    f32x4 po1 = (f32x4){0.f, 0.f, 0.f, 0.f};
    int pw_sub = 4 * (g & 1);
    int c7 = c & 7;
#pragma unroll
    for (int ck = 0; ck < 5; ++ck) {
#pragma unroll
      for (int t = 0; t < 2; ++t) {
        int mt = 2 * ck + t;
        u16* dst = qn + n * 64 + ((2 * t + (g >> 1)) ^ c7) * 8 + pw_sub;
        if (mt < 9) {
          *(u32*)dst = cvtpk(ST[mt][0] * rinv, ST[mt][1] * rinv);
          *(u32*)(dst + 2) = cvtpk(ST[mt][2] * rinv, ST[mt][3] * rinv);
        } else {
          *(u32*)dst = 0u;
          *(u32*)(dst + 2) = 0u;
        }
      }
      short8 pa = *(const short8*)(qn + n * 64 + fswz);
      short8 vbf0 = *(const short8*)(vT + c * 192 + ((4 * ck + g) ^ c7) * 8);
      short8 vbf1 = *(const short8*)(vT + (16 + c) * 192 + ((4 * ck + g) ^ c7) * 8);
      po0 = MFMA(pa, vbf0, po0);
      po1 = MFMA(pa, vbf1, po1);
    }
    // epilogue: O C-layout row = n (g*4+r), col = d (c)
#pragma unroll
    for (int r = 0; r < 4; ++r) {
      int nn = rbase + nt * 16 + g * 4 + r;
      u16* crow = ctx + ((size_t)b * NTOK + nn) * DIMC + h * 32;
      crow[c] = f2bf(po0[r]);
      crow[16 + c] = f2bf(po1[r]);
    }
  }
}

// ---------------- output projection: (73728 x 384) @ (384 x 384)^T + bias, bf16 MFMA ----------------
__global__ __launch_bounds__(256) void proj_gemm(const u16* __restrict__ ctx,
                                                 const u16* __restrict__ pwb,
                                                 const float* __restrict__ proj_b,
                                                 float* __restrict__ out) {
  __shared__ u16 As[128 * 64];
  __shared__ u16 Bs[128 * 64];
  int bid = blockIdx.x;
  int nblk = bid % 3, mblk = bid / 3;
  size_t gm0 = (size_t)mblk * 128;
  int gn0 = nblk * 128;
  int tid = threadIdx.x, lane = tid & 63, wid = tid >> 6;
  int wr = wid >> 1, wc = wid & 1, g = lane >> 4, c = lane & 15;
  f32x4 acc[4][4];
#pragma unroll
  for (int i = 0; i < 4; ++i)
#pragma unroll
    for (int j = 0; j < 4; ++j) acc[i][j] = (f32x4){0.f, 0.f, 0.f, 0.f};

  for (int t = 0; t < 6; ++t) {
    int k0 = t * 64;
#pragma unroll
    for (int p = 0; p < 4; ++p) {
      int row = p * 32 + (tid >> 3);
      int seg = (tid & 7) * 8;
      uint4 va = *(const uint4*)(ctx + (gm0 + row) * DIMC + k0 + seg);
      *(uint4*)(As + row * 64 + seg) = va;
      uint4 vb = *(const uint4*)(pwb + (size_t)(gn0 + row) * DIMC + k0 + seg);
      *(uint4*)(Bs + row * 64 + seg) = vb;
    }
    __syncthreads();
#pragma unroll
    for (int kk = 0; kk < 64; kk += 32) {
      short8 a[4], bfr[4];
#pragma unroll
      for (int mi = 0; mi < 4; ++mi)
        a[mi] = *(const short8*)(As + (wr * 64 + mi * 16 + c) * 64 + kk + g * 8);
#pragma unroll
      for (int ni = 0; ni < 4; ++ni)
        bfr[ni] = *(const short8*)(Bs + (wc * 64 + ni * 16 + c) * 64 + kk + g * 8);
#pragma unroll
      for (int mi = 0; mi < 4; ++mi)
#pragma unroll
        for (int ni = 0; ni < 4; ++ni)
          acc[mi][ni] = MFMA(a[mi], bfr[ni], acc[mi][ni]);
    }
    __syncthreads();
  }
#pragma unroll
  for (int mi = 0; mi < 4; ++mi)
#pragma unroll
    for (int ni = 0; ni < 4; ++ni) {
      int gcol = gn0 + wc * 64 + ni * 16 + c;
      float bv = proj_b[gcol];
#pragma unroll
      for (int r = 0; r < 4; ++r) {
        size_t grow = gm0 + wr * 64 + mi * 16 + g * 4 + r;
        out[grow * DIMC + gcol] = acc[mi][ni][r] + bv;
      }
    }
}

extern "C" void kernel_launch(void* const* d_in, const int* in_sizes, int n_in,
                              void* d_out, int out_size, void* d_ws, size_t ws_size,
                              hipStream_t stream) {
  const float* x = (const float*)d_in[0];
  const float* rct = (const float*)d_in[1];
  const int* rpi = (const int*)d_in[2];
  const float* mask = (const float*)d_in[3];
  const float* qkv_w = (const float*)d_in[4];
  const float* q_bias = (const float*)d_in[5];
  const float* k_bias = (const float*)d_in[6];
  const float* v_bias = (const float*)d_in[7];
  const float* logit_scale = (const float*)d_in[8];
  const float* cpb_w1 = (const float*)d_in[9];
  const float* cpb_b1 = (const float*)d_in[10];
  const float* cpb_w2 = (const float*)d_in[11];
  const float* proj_w = (const float*)d_in[12];
  const float* proj_b = (const float*)d_in[13];
  float* out = (float*)d_out;

  char* ws = (char*)d_ws;
  size_t off = 0;
  auto alloc = [&](size_t bytes) {
    void* p = ws + off;
    off = (off + bytes + 255) & ~(size_t)255;
    return p;
  };
  const size_t NX = (size_t)BWIN * NTOK * DIMC;  // 28311552
  u16* xb = (u16*)alloc(NX * 2);
  u16* wqb = (u16*)alloc((size_t)3 * DIMC * DIMC * 2);
  u16* pwb = (u16*)alloc((size_t)DIMC * DIMC * 2);
  u16* ctx = (u16*)alloc(NX * 2);
  float* tabT = (float*)alloc((size_t)NHEADS * TABLEN * 4);
  float* scalev = (float*)alloc(64 * 4);

  cvt_bf16<<<(int)(NX / 8 + 255) / 256, 256, 0, stream>>>(x, xb, (int)(NX / 8));
  cvt_bf16<<<(3 * DIMC * DIMC / 8 + 255) / 256, 256, 0, stream>>>(qkv_w, wqb, 3 * DIMC * DIMC / 8);
  cvt_bf16<<<(DIMC * DIMC / 8 + 255) / 256, 256, 0, stream>>>(proj_w, pwb, DIMC * DIMC / 8);
  cpb_kernel<<<(TABLEN * NHEADS + 255) / 256, 256, 0, stream>>>(
      rct, cpb_w1, cpb_b1, cpb_w2, logit_scale, tabT, scalev);
  attn_fused<<<BWIN * NHEADS, 192, 0, stream>>>(
      xb, wqb, q_bias, k_bias, v_bias, rpi, mask, tabT, scalev, ctx);
  proj_gemm<<<(BWIN * NTOK / 128) * 3, 256, 0, stream>>>(ctx, pwb, proj_b, out);
}

// Round 4
// 372.590 us; speedup vs baseline: 1.3645x; 1.3645x over previous
//
#include <hip/hip_runtime.h>

#define DIMC 384
#define NHEADS 12
#define NTOK 144
#define TABLEN 529
#define BWIN 512
#define NWIN 16
#define CPBH 512

typedef unsigned short u16;
typedef unsigned int u32;
typedef __attribute__((ext_vector_type(8))) short short8;
typedef __attribute__((ext_vector_type(4))) float f32x4;

#define MFMA(a, b, c) __builtin_amdgcn_mfma_f32_16x16x32_bf16((a), (b), (c), 0, 0, 0)

__device__ __forceinline__ u16 f2bf(float f) {
  union { float f; u32 u; } v; v.f = f;
  u32 r = v.u + 0x7fffu + ((v.u >> 16) & 1u);
  return (u16)(r >> 16);
}
__device__ __forceinline__ u32 pk2(float a, float b) {
  return (u32)f2bf(a) | ((u32)f2bf(b) << 16);
}
__device__ __forceinline__ u32 cvtpk(float lo, float hi) {
  u32 r;
  asm("v_cvt_pk_bf16_f32 %0, %1, %2" : "=v"(r) : "v"(lo), "v"(hi));
  return r;
}

// ---------------- f32 -> bf16 bulk convert (8 elems/thread) ----------------
__global__ __launch_bounds__(256) void cvt_bf16(const float* __restrict__ in,
                                                u16* __restrict__ out, int n8) {
  int i = blockIdx.x * 256 + threadIdx.x;
  if (i >= n8) return;
  const float4* p = (const float4*)(in + (size_t)i * 8);
  float4 a = p[0], b = p[1];
  uint4 r;
  r.x = pk2(a.x, a.y); r.y = pk2(a.z, a.w);
  r.z = pk2(b.x, b.y); r.w = pk2(b.z, b.w);
  *(uint4*)(out + (size_t)i * 8) = r;
}

// ---------------- CPB-MLP: tabT[h][529] = 16*sigmoid(mlp) + per-head scales ----------------
__global__ void cpb_kernel(const float* __restrict__ rct,
                           const float* __restrict__ w1,
                           const float* __restrict__ b1,
                           const float* __restrict__ w2,
                           const float* __restrict__ logit_scale,
                           float* __restrict__ tabT,
                           float* __restrict__ scalev) {
  int t = blockIdx.x * blockDim.x + threadIdx.x;
  if (t < NHEADS) scalev[t] = __expf(fminf(logit_scale[t], 4.60517018598809f));
  if (t >= TABLEN * NHEADS) return;
  int i = t / NHEADS, h = t % NHEADS;
  float c0 = rct[2 * i], c1 = rct[2 * i + 1];
  const float* w2h = w2 + (size_t)h * CPBH;
  float acc = 0.f;
  for (int k = 0; k < CPBH; ++k) {
    float hv = fmaxf(0.f, fmaf(c0, w1[2 * k], fmaf(c1, w1[2 * k + 1], b1[k])));
    acc = fmaf(hv, w2h[k], acc);
  }
  tabT[h * TABLEN + i] = 16.f / (1.f + __expf(-acc));
}

// ---------------- fused QKV-projection + cosine attention per (window b, head h) ----------------
// 192 threads = 3 waves; wave wv owns query rows [48wv, 48wv+48).
// Block mapping is XCD-chunked: all 12 heads of a window land on one XCD's L2.
__global__ __launch_bounds__(192, 2) void attn_fused(
    const float* __restrict__ x, const u16* __restrict__ wb,
    const float* __restrict__ q_bias, const float* __restrict__ k_bias,
    const float* __restrict__ v_bias, const int* __restrict__ rpi,
    const float* __restrict__ mask, const float* __restrict__ tabT,
    const float* __restrict__ scalev, u16* __restrict__ ctx) {
  __shared__ u16 smem[25640];
  u16* qn = smem;            // [144][64] swizzled; P-bounce alias in PV phase
  u16* xs = smem + 9216;     // phase1: x chunk | phase2+: kn [144][64]
  u16* wsm = smem + 18432;   // phase1: W chunk | phase2+: vT [32][192]
  u16* kn = smem + 9216;
  u16* vT = smem + 18432;
  float* tab = (float*)(smem + 24576);

  // XCD-chunked decode (dispatch round-robins blockIdx across 8 XCDs)
  int bid = blockIdx.x;
  int xcd = bid & 7, slot = bid >> 3;
  int b = xcd * 64 + slot / NHEADS;
  int h = slot % NHEADS;
  int tid = threadIdx.x;
  int lane = tid & 63, wv = tid >> 6;
  int g = lane >> 4, c = lane & 15;
  int rbase = wv * 48;

  for (int i = tid; i < TABLEN; i += 192) tab[i] = tabT[h * TABLEN + i];

  // ---- phase 1: QKV projection (per-head 96 outputs), K chunked by 32 ----
  f32x4 acc[3][6];
#pragma unroll
  for (int i = 0; i < 3; ++i)
#pragma unroll
    for (int j = 0; j < 6; ++j) acc[i][j] = (f32x4){0.f, 0.f, 0.f, 0.f};

  int r4 = tid >> 2, s8 = (tid & 3) * 8;
  int xswz = ((tid & 3) ^ (r4 & 7)) * 8;
  float4 pxa[3], pxb[3];
  uint4 pw[2];
#pragma unroll
  for (int p = 0; p < 3; ++p) {
    const float* xr = x + ((size_t)b * NTOK + p * 48 + r4) * DIMC + s8;
    pxa[p] = *(const float4*)xr;
    pxb[p] = *(const float4*)(xr + 4);
  }
#pragma unroll
  for (int p = 0; p < 2; ++p) {
    int row = p * 48 + r4;
    int wrow = (row >> 5) * DIMC + h * 32 + (row & 31);
    pw[p] = *(const uint4*)(wb + (size_t)wrow * DIMC + s8);
  }

  for (int t = 0; t < 12; ++t) {
#pragma unroll
    for (int p = 0; p < 3; ++p) {
      uint4 v;
      v.x = cvtpk(pxa[p].x, pxa[p].y);
      v.y = cvtpk(pxa[p].z, pxa[p].w);
      v.z = cvtpk(pxb[p].x, pxb[p].y);
      v.w = cvtpk(pxb[p].z, pxb[p].w);
      *(uint4*)(xs + (p * 48 + r4) * 64 + xswz) = v;
    }
#pragma unroll
    for (int p = 0; p < 2; ++p)
      *(uint4*)(wsm + (p * 48 + r4) * 64 + xswz) = pw[p];
    __syncthreads();
    if (t < 11) {
      int k0 = (t + 1) * 32;
#pragma unroll
      for (int p = 0; p < 3; ++p) {
        const float* xr = x + ((size_t)b * NTOK + p * 48 + r4) * DIMC + k0 + s8;
        pxa[p] = *(const float4*)xr;
        pxb[p] = *(const float4*)(xr + 4);
      }
#pragma unroll
      for (int p = 0; p < 2; ++p) {
        int row = p * 48 + r4;
        int wrow = (row >> 5) * DIMC + h * 32 + (row & 31);
        pw[p] = *(const uint4*)(wb + (size_t)wrow * DIMC + k0 + s8);
      }
    }
    int fswz = (g ^ (c & 7)) * 8;
    short8 ax[3];
#pragma unroll
    for (int nt = 0; nt < 3; ++nt)
      ax[nt] = *(const short8*)(xs + (rbase + nt * 16 + c) * 64 + fswz);
#pragma unroll
    for (int ni = 0; ni < 6; ++ni) {
      short8 bw = *(const short8*)(wsm + (ni * 16 + c) * 64 + fswz);
#pragma unroll
      for (int nt = 0; nt < 3; ++nt) acc[nt][ni] = MFMA(ax[nt], bw, acc[nt][ni]);
    }
    __syncthreads();
  }

  // ---- phase 2: bias + cosine-normalize, write qn/kn (u16) + vT (packed u32) ----
  float sch = scalev[h];
  float qb0 = q_bias[h * 32 + c], qb1 = q_bias[h * 32 + 16 + c];
  float kb0 = k_bias[h * 32 + c], kb1 = k_bias[h * 32 + 16 + c];
  float vb0 = v_bias[h * 32 + c], vb1 = v_bias[h * 32 + 16 + c];
#pragma unroll
  for (int nt = 0; nt < 3; ++nt) {
    float v0a[4], v1a[4];
#pragma unroll
    for (int r = 0; r < 4; ++r) {
      int row = rbase + nt * 16 + g * 4 + r;
      int rw7 = row & 7;
      float q0 = acc[nt][0][r] + qb0, q1 = acc[nt][1][r] + qb1;
      float ssq = q0 * q0 + q1 * q1;
      ssq += __shfl_xor(ssq, 1); ssq += __shfl_xor(ssq, 2);
      ssq += __shfl_xor(ssq, 4); ssq += __shfl_xor(ssq, 8);
      float siq = sch / sqrtf(ssq);
      qn[row * 64 + ((c >> 3) ^ rw7) * 8 + (c & 7)] = f2bf(q0 * siq);
      qn[row * 64 + (((c + 16) >> 3) ^ rw7) * 8 + (c & 7)] = f2bf(q1 * siq);
      float k0v = acc[nt][2][r] + kb0, k1v = acc[nt][3][r] + kb1;
      float ssk = k0v * k0v + k1v * k1v;
      ssk += __shfl_xor(ssk, 1); ssk += __shfl_xor(ssk, 2);
      ssk += __shfl_xor(ssk, 4); ssk += __shfl_xor(ssk, 8);
      float sik = 1.f / sqrtf(ssk);
      kn[row * 64 + ((c >> 3) ^ rw7) * 8 + (c & 7)] = f2bf(k0v * sik);
      kn[row * 64 + (((c + 16) >> 3) ^ rw7) * 8 + (c & 7)] = f2bf(k1v * sik);
      v0a[r] = acc[nt][4][r] + vb0;
      v1a[r] = acc[nt][5][r] + vb1;
    }
    int m0 = rbase + nt * 16 + g * 4;
    int blk = m0 >> 3;
    int sub = m0 & 7;
    u16* p0 = vT + c * 192 + (blk ^ (c & 7)) * 8 + sub;
    u16* p1 = vT + (c + 16) * 192 + (blk ^ (c & 7)) * 8 + sub;
    *(u32*)p0 = cvtpk(v0a[0], v0a[1]);
    *(u32*)(p0 + 2) = cvtpk(v0a[2], v0a[3]);
    *(u32*)p1 = cvtpk(v1a[0], v1a[1]);
    *(u32*)(p1 + 2) = cvtpk(v1a[2], v1a[3]);
  }
  if (tid < 64) {  // zero vT m-pad (144..159)
    int d = tid >> 1, t = tid & 1;
    uint4 z4 = {0u, 0u, 0u, 0u};
    *(uint4*)(vT + d * 192 + ((18 + t) ^ (d & 7)) * 8) = z4;
  }
  __syncthreads();

  // ---- phases 3-5 per nt: S^T = kn.qn^T, softmax in-lane, packed-P bounce, PV ----
  int fswz = (g ^ (c & 7)) * 8;
  int w = b & (NWIN - 1);

#pragma unroll
  for (int nt = 0; nt < 3; ++nt) {
    int n = rbase + nt * 16 + c;
    short8 bq = *(const short8*)(qn + n * 64 + fswz);
    f32x4 ST[9];
#pragma unroll
    for (int mt = 0; mt < 9; ++mt) {
      short8 ak = *(const short8*)(kn + (mt * 16 + c) * 64 + fswz);
      f32x4 z = (f32x4){0.f, 0.f, 0.f, 0.f};
      ST[mt] = MFMA(ak, bq, z);
    }
    // bias add + max
    const int* rrow = rpi + n * NTOK;
    const float* mrow = mask + ((size_t)(w * NTOK + n)) * NTOK;
    float mx = -1e30f;
#pragma unroll
    for (int mt = 0; mt < 9; ++mt) {
      int4 idx = *(const int4*)(rrow + mt * 16 + g * 4);
      float4 mk = *(const float4*)(mrow + mt * 16 + g * 4);
      ST[mt][0] += tab[idx.x] + mk.x;
      ST[mt][1] += tab[idx.y] + mk.y;
      ST[mt][2] += tab[idx.z] + mk.z;
      ST[mt][3] += tab[idx.w] + mk.w;
      mx = fmaxf(mx, fmaxf(fmaxf(ST[mt][0], ST[mt][1]), fmaxf(ST[mt][2], ST[mt][3])));
    }
    mx = fmaxf(mx, __shfl_xor(mx, 16));
    mx = fmaxf(mx, __shfl_xor(mx, 32));
    float sum = 0.f;
#pragma unroll
    for (int mt = 0; mt < 9; ++mt) {
#pragma unroll
      for (int r = 0; r < 4; ++r) {
        float p = __expf(ST[mt][r] - mx);
        ST[mt][r] = p;
        sum += p;
      }
    }
    sum += __shfl_xor(sum, 16);
    sum += __shfl_xor(sum, 32);
    float rinv = 1.f / sum;

    // PV: per-32-m-chunk packed-P bounce into (dead) qn region, rows wave-private
    f32x4 po0 = (f32x4){0.f, 0.f, 0.f, 0.f};
    f32x4 po1 = (f32x4){0.f, 0.f, 0.f, 0.f};
    int pw_sub = 4 * (g & 1);
    int c7 = c & 7;
#pragma unroll
    for (int ck = 0; ck < 5; ++ck) {
#pragma unroll
      for (int t = 0; t < 2; ++t) {
        int mt = 2 * ck + t;
        u16* dst = qn + n * 64 + ((2 * t + (g >> 1)) ^ c7) * 8 + pw_sub;
        if (mt < 9) {
          *(u32*)dst = cvtpk(ST[mt][0] * rinv, ST[mt][1] * rinv);
          *(u32*)(dst + 2) = cvtpk(ST[mt][2] * rinv, ST[mt][3] * rinv);
        } else {
          *(u32*)dst = 0u;
          *(u32*)(dst + 2) = 0u;
        }
      }
      short8 pa = *(const short8*)(qn + n * 64 + fswz);
      short8 vbf0 = *(const short8*)(vT + c * 192 + ((4 * ck + g) ^ c7) * 8);
      short8 vbf1 = *(const short8*)(vT + (16 + c) * 192 + ((4 * ck + g) ^ c7) * 8);
      po0 = MFMA(pa, vbf0, po0);
      po1 = MFMA(pa, vbf1, po1);
    }
    // epilogue: O C-layout row = n (g*4+r), col = d (c)
#pragma unroll
    for (int r = 0; r < 4; ++r) {
      int nn = rbase + nt * 16 + g * 4 + r;
      u16* crow = ctx + ((size_t)b * NTOK + nn) * DIMC + h * 32;
      crow[c] = f2bf(po0[r]);
      crow[16 + c] = f2bf(po1[r]);
    }
  }
}

// ---------------- output projection: (73728 x 384) @ (384 x 384)^T + bias, bf16 MFMA ----------------
__global__ __launch_bounds__(256) void proj_gemm(const u16* __restrict__ ctx,
                                                 const u16* __restrict__ pwb,
                                                 const float* __restrict__ proj_b,
                                                 float* __restrict__ out) {
  __shared__ u16 As[128 * 64];
  __shared__ u16 Bs[128 * 64];
  int bid = blockIdx.x;
  int nblk = bid % 3, mblk = bid / 3;
  size_t gm0 = (size_t)mblk * 128;
  int gn0 = nblk * 128;
  int tid = threadIdx.x, lane = tid & 63, wid = tid >> 6;
  int wr = wid >> 1, wc = wid & 1, g = lane >> 4, c = lane & 15;
  f32x4 acc[4][4];
#pragma unroll
  for (int i = 0; i < 4; ++i)
#pragma unroll
    for (int j = 0; j < 4; ++j) acc[i][j] = (f32x4){0.f, 0.f, 0.f, 0.f};

  for (int t = 0; t < 6; ++t) {
    int k0 = t * 64;
#pragma unroll
    for (int p = 0; p < 4; ++p) {
      int row = p * 32 + (tid >> 3);
      int seg = (tid & 7) * 8;
      uint4 va = *(const uint4*)(ctx + (gm0 + row) * DIMC + k0 + seg);
      *(uint4*)(As + row * 64 + seg) = va;
      uint4 vb = *(const uint4*)(pwb + (size_t)(gn0 + row) * DIMC + k0 + seg);
      *(uint4*)(Bs + row * 64 + seg) = vb;
    }
    __syncthreads();
#pragma unroll
    for (int kk = 0; kk < 64; kk += 32) {
      short8 a[4], bfr[4];
#pragma unroll
      for (int mi = 0; mi < 4; ++mi)
        a[mi] = *(const short8*)(As + (wr * 64 + mi * 16 + c) * 64 + kk + g * 8);
#pragma unroll
      for (int ni = 0; ni < 4; ++ni)
        bfr[ni] = *(const short8*)(Bs + (wc * 64 + ni * 16 + c) * 64 + kk + g * 8);
#pragma unroll
      for (int mi = 0; mi < 4; ++mi)
#pragma unroll
        for (int ni = 0; ni < 4; ++ni)
          acc[mi][ni] = MFMA(a[mi], bfr[ni], acc[mi][ni]);
    }
    __syncthreads();
  }
#pragma unroll
  for (int mi = 0; mi < 4; ++mi)
#pragma unroll
    for (int ni = 0; ni < 4; ++ni) {
      int gcol = gn0 + wc * 64 + ni * 16 + c;
      float bv = proj_b[gcol];
#pragma unroll
      for (int r = 0; r < 4; ++r) {
        size_t grow = gm0 + wr * 64 + mi * 16 + g * 4 + r;
        out[grow * DIMC + gcol] = acc[mi][ni][r] + bv;
      }
    }
}

extern "C" void kernel_launch(void* const* d_in, const int* in_sizes, int n_in,
                              void* d_out, int out_size, void* d_ws, size_t ws_size,
                              hipStream_t stream) {
  const float* x = (const float*)d_in[0];
  const float* rct = (const float*)d_in[1];
  const int* rpi = (const int*)d_in[2];
  const float* mask = (const float*)d_in[3];
  const float* qkv_w = (const float*)d_in[4];
  const float* q_bias = (const float*)d_in[5];
  const float* k_bias = (const float*)d_in[6];
  const float* v_bias = (const float*)d_in[7];
  const float* logit_scale = (const float*)d_in[8];
  const float* cpb_w1 = (const float*)d_in[9];
  const float* cpb_b1 = (const float*)d_in[10];
  const float* cpb_w2 = (const float*)d_in[11];
  const float* proj_w = (const float*)d_in[12];
  const float* proj_b = (const float*)d_in[13];
  float* out = (float*)d_out;

  char* ws = (char*)d_ws;
  size_t off = 0;
  auto alloc = [&](size_t bytes) {
    void* p = ws + off;
    off = (off + bytes + 255) & ~(size_t)255;
    return p;
  };
  const size_t NX = (size_t)BWIN * NTOK * DIMC;  // 28311552
  u16* wqb = (u16*)alloc((size_t)3 * DIMC * DIMC * 2);
  u16* pwb = (u16*)alloc((size_t)DIMC * DIMC * 2);
  u16* ctx = (u16*)alloc(NX * 2);
  float* tabT = (float*)alloc((size_t)NHEADS * TABLEN * 4);
  float* scalev = (float*)alloc(64 * 4);

  cvt_bf16<<<(3 * DIMC * DIMC / 8 + 255) / 256, 256, 0, stream>>>(qkv_w, wqb, 3 * DIMC * DIMC / 8);
  cvt_bf16<<<(DIMC * DIMC / 8 + 255) / 256, 256, 0, stream>>>(proj_w, pwb, DIMC * DIMC / 8);
  cpb_kernel<<<(TABLEN * NHEADS + 255) / 256, 256, 0, stream>>>(
      rct, cpb_w1, cpb_b1, cpb_w2, logit_scale, tabT, scalev);
  attn_fused<<<BWIN * NHEADS, 192, 0, stream>>>(
      x, wqb, q_bias, k_bias, v_bias, rpi, mask, tabT, scalev, ctx);
  proj_gemm<<<(BWIN * NTOK / 128) * 3, 256, 0, stream>>>(ctx, pwb, proj_b, out);
}